// Round 3
// baseline (918.838 us; speedup 1.0000x reference)
//
#include <hip/hip_runtime.h>
#include <math.h>

// global_powermean_pooling, P = 2.0
//   out[g, d] = sqrt( mean_{n : batch[n]==g} x[n, d]^2 ),  empty segment -> 0
// x: [N, 128] fp32, batch: [N] int32 sorted ascending in [0, G)
//
// R3 = MEASUREMENT ROUND: kernel B is launched 4x (idempotent) so that
//   dur_us(R3) - dur_us(R2) = 3 * B_time,
// isolating kernel B's true duration from the fixed harness restore/poison
// traffic that dominates dur_us. Kernels themselves are unchanged from R2.

#define D_FEAT 128
#define DV (D_FEAT / 4)  // 32 float4 per row

// ---- Kernel A: segment offsets ------------------------------------------
__global__ __launch_bounds__(256) void seg_offsets_kernel(
    const int* __restrict__ batch, int* __restrict__ off, int N, int G)
{
    int i = blockIdx.x * blockDim.x + threadIdx.x;
    if (i >= N) return;
    int cur = batch[i];
    if (i == 0) {
        for (int g = 0; g <= cur; ++g) off[g] = 0;   // segments before first id
    } else {
        int prev = batch[i - 1];
        for (int g = prev + 1; g <= cur; ++g) off[g] = i;
    }
    if (i == N - 1) {
        for (int g = cur + 1; g <= G; ++g) off[g] = N;  // trailing empties + off[G]
    }
}

// ---- Kernel B: per-graph power-mean pooling ------------------------------
__global__ __launch_bounds__(256) void global_powermean_pooling_44126493999223_kernel(
    const float* __restrict__ x,
    const int* __restrict__ off,
    float* __restrict__ out)
{
    const int g    = blockIdx.x;
    const int tid  = threadIdx.x;
    const int fg   = tid & 31;   // float4 index within the 128-wide row
    const int lane = tid >> 5;   // node-lane 0..7

    const int start = off[g];
    const int end   = off[g + 1];
    const int count = end - start;

    const float4* __restrict__ x4 = (const float4*)x;

    float4 a0 = make_float4(0.f, 0.f, 0.f, 0.f);
    float4 a1 = a0, a2 = a0, a3 = a0;

    // 4x unrolled: 4 independent 1KB wave-loads in flight per iteration.
    int r = start + lane;
    for (; r + 24 < end; r += 32) {
        float4 v0 = x4[(size_t)(r     ) * DV + fg];
        float4 v1 = x4[(size_t)(r +  8) * DV + fg];
        float4 v2 = x4[(size_t)(r + 16) * DV + fg];
        float4 v3 = x4[(size_t)(r + 24) * DV + fg];
        a0.x += v0.x * v0.x; a0.y += v0.y * v0.y; a0.z += v0.z * v0.z; a0.w += v0.w * v0.w;
        a1.x += v1.x * v1.x; a1.y += v1.y * v1.y; a1.z += v1.z * v1.z; a1.w += v1.w * v1.w;
        a2.x += v2.x * v2.x; a2.y += v2.y * v2.y; a2.z += v2.z * v2.z; a2.w += v2.w * v2.w;
        a3.x += v3.x * v3.x; a3.y += v3.y * v3.y; a3.z += v3.z * v3.z; a3.w += v3.w * v3.w;
    }
    for (; r < end; r += 8) {
        float4 v = x4[(size_t)r * DV + fg];
        a0.x += v.x * v.x; a0.y += v.y * v.y; a0.z += v.z * v.z; a0.w += v.w * v.w;
    }
    a0.x += a1.x + a2.x + a3.x;
    a0.y += a1.y + a2.y + a3.y;
    a0.z += a1.z + a2.z + a3.z;
    a0.w += a1.w + a2.w + a3.w;

    __shared__ float4 red[256];
    red[tid] = a0;
    __syncthreads();
    for (int o = 4; o >= 1; o >>= 1) {
        if (lane < o) {
            float4 a = red[tid];
            float4 b = red[tid + o * 32];
            a.x += b.x; a.y += b.y; a.z += b.z; a.w += b.w;
            red[tid] = a;
        }
        __syncthreads();
    }

    if (lane == 0) {
        const float inv = 1.0f / (float)(count > 0 ? count : 1);
        float4 s = red[tid];
        float4 o;
        o.x = sqrtf(s.x * inv);
        o.y = sqrtf(s.y * inv);
        o.z = sqrtf(s.z * inv);
        o.w = sqrtf(s.w * inv);
        ((float4*)out)[(size_t)g * DV + fg] = o;   // 32 lanes -> 512B contiguous
    }
}

extern "C" void kernel_launch(void* const* d_in, const int* in_sizes, int n_in,
                              void* d_out, int out_size, void* d_ws, size_t ws_size,
                              hipStream_t stream) {
    const float* x     = (const float*)d_in[0];
    const int*   batch = (const int*)d_in[1];
    float*       out   = (float*)d_out;

    const int N = in_sizes[1];           // 1,000,000 nodes
    const int G = out_size / D_FEAT;     // 4096 graphs

    int* off = (int*)d_ws;               // G+1 ints (16.4 KB of the 2 GB ws)

    seg_offsets_kernel<<<(N + 255) / 256, 256, 0, stream>>>(batch, off, N, G);

    // MEASUREMENT: 4 identical launches; delta vs R2 = 3 * B_time.
    global_powermean_pooling_44126493999223_kernel<<<G, 256, 0, stream>>>(x, off, out);
    global_powermean_pooling_44126493999223_kernel<<<G, 256, 0, stream>>>(x, off, out);
    global_powermean_pooling_44126493999223_kernel<<<G, 256, 0, stream>>>(x, off, out);
    global_powermean_pooling_44126493999223_kernel<<<G, 256, 0, stream>>>(x, off, out);
}